// Round 3
// baseline (337.483 us; speedup 1.0000x reference)
//
#include <hip/hip_runtime.h>
#include <stdint.h>

// Gator: logic-gate network forward, bit-packed over batch.
//
// R7: ballot-free parallel bit-pack. R5/R6 proved the store stream is at its
// floor (~50-55us) in ANY structure (NT-scattered == regular-contiguous ==
// fused, all ~330us total). The invariant across all rounds is phase A+B
// (unchanged since R3) at 1 block/CU -- and the old R4 result (redundant A+B
// at 2 blocks/CU REGRESSED) independently fingers A+B as the ~80us component.
// This round:
//   K1 gator_packx: phase A without ballots/LDS. 1024 blocks x 256 thr,
//      each thread builds one column-word by 32 unrolled stride-4KB loads
//      (256B/instr coalesced across lanes, 32 loads in flight/thread,
//      many blocks/CU). 33.5MB read -> ~6us BW-bound.
//   K2 gator_gates: phase B only. LDS seeded by one coalesced 4KB ws read,
//      8 gate rows (verified logic unchanged), dump rows W0..WTOT.
//   K3 gator_unpack: R6's contiguous-row streamer (verified, at floor).
// Prediction: dur 336 -> ~280 if phase A was the cost; ~335 if phase B /
// harness overhead is. Kernel HBM floor ~57us + fill ~190us.

constexpr int B    = 8192;
constexpr int W0   = 1024;
constexpr int R    = 8;
constexpr int G    = 1024;
constexpr int WTOT = W0 + R * G;   // 9216
constexpr int BPB  = 32;           // batch bits per pack group
constexpr int NBG  = B / BPB;      // 256 pack groups

typedef float vfloat4 __attribute__((ext_vector_type(4)));

// ---------------- K1: coalesced ballot-free bit-pack of x -------------------
// Block (bg, chunk): lanes own columns chunk*256+tid. Lane builds bit b of
// its column word from x[bg*32+b][col]; consecutive lanes -> consecutive
// 4B addresses (perfectly coalesced 256B/instr); the 32 row-loads are
// independent and fully unrolled. No LDS, tiny VGPR -> high occupancy.
__launch_bounds__(256, 8)
__global__ void gator_packx(const float* __restrict__ x,
                            uint32_t*    __restrict__ packed) {
    const int bg    = blockIdx.x >> 2;
    const int chunk = blockIdx.x & 3;
    const int col   = chunk * 256 + threadIdx.x;
    const float* xcol = x + (size_t)bg * BPB * W0 + col;
    uint32_t o = 0;
    #pragma unroll
    for (int b = 0; b < BPB; ++b) {
        o |= (xcol[(size_t)b * W0] != 0.0f ? 1u : 0u) << b;
    }
    packed[(size_t)bg * WTOT + col] = o;
}

// ---------------- K2: gate rows (phase B) -----------------------------------
__launch_bounds__(1024, 1)
__global__ void gator_gates(const float* __restrict__ gates,
                            const int*   __restrict__ choices,
                            uint32_t*    __restrict__ packed) {
    __shared__ uint32_t cols[WTOT];

    const int tid = threadIdx.x;
    const int bg  = blockIdx.x;

    // Prefetch gate metadata for all 8 rows into registers (off the barrier
    // chain; overlaps the LDS seed).
    const int2*   ch2 = (const int2*)choices;    // [R*G] index pairs
    const float4* g4  = (const float4*)gates;    // [R*G] truth tables
    int2     ch[R];
    uint32_t tt[R];                              // 4-bit truth table mask
    #pragma unroll
    for (int r = 0; r < R; ++r) {
        ch[r] = ch2[r * G + tid];
        float4 lt = g4[r * G + tid];
        tt[r] = (lt.x != 0.0f ? 1u : 0u) | (lt.y != 0.0f ? 2u : 0u) |
                (lt.z != 0.0f ? 4u : 0u) | (lt.w != 0.0f ? 8u : 0u);
    }

    // Seed LDS with the W0 packed input columns: one coalesced 4KB read.
    cols[tid] = packed[(size_t)bg * WTOT + tid];
    __syncthreads();

    // 8 gate rows, one gate per thread per row (verified logic).
    #pragma unroll
    for (int r = 0; r < R; ++r) {
        uint32_t a = cols[ch[r].x];
        uint32_t b = cols[ch[r].y];
        uint32_t m0 = 0u - (tt[r] & 1u);
        uint32_t m1 = 0u - ((tt[r] >> 1) & 1u);
        uint32_t m2 = 0u - ((tt[r] >> 2) & 1u);
        uint32_t m3 = 0u - ((tt[r] >> 3) & 1u);
        uint32_t o = (m0 & ~a & ~b) | (m1 & ~a & b) | (m2 & a & ~b) | (m3 & a & b);
        cols[W0 + r * G + tid] = o;
        __syncthreads();
    }

    // Dump the 8 new row blocks (8192 words = 32KB, coalesced 16B).
    uint32_t* prow = packed + (size_t)bg * WTOT;
    #pragma unroll
    for (int w = W0 + tid * 4; w < WTOT; w += 4096) {
        *(uint4*)&prow[w] = *(const uint4*)&cols[w];
    }
}

// ---------------- K3: contiguous-row streaming unpack (R6, verified) --------
// One block per batch row; 36,864B fully contiguous regular float4 stores.
__launch_bounds__(256, 8)
__global__ void gator_unpack(const uint32_t* __restrict__ packed,
                             float*          __restrict__ out) {
    const int row = blockIdx.x;          // batch row 0..8191
    const int bg  = row >> 5;
    const int bit = row & 31;
    const uint32_t* prow = packed + (size_t)bg * WTOT;
    float*          orow = out + (size_t)row * WTOT;

    #pragma unroll
    for (int it = 0; it < WTOT / 1024; ++it) {   // 9 iterations
        const int w = it * 1024 + threadIdx.x * 4;
        uint4 c = *(const uint4*)&prow[w];
        vfloat4 v;
        v.x = (float)((c.x >> bit) & 1u);
        v.y = (float)((c.y >> bit) & 1u);
        v.z = (float)((c.z >> bit) & 1u);
        v.w = (float)((c.w >> bit) & 1u);
        *(vfloat4*)(orow + w) = v;
    }
}

// ---------------- Fallback: R3 fused kernel (verified) ----------------------
__launch_bounds__(1024, 1)
__global__ void gator_fused(const float* __restrict__ x,
                            const float* __restrict__ gates,
                            const int*   __restrict__ choices,
                            float*       __restrict__ out) {
    __shared__ uint32_t cols[WTOT];

    const int tid  = threadIdx.x;
    const int lane = tid & 63;
    const int wv   = tid >> 6;
    const int bg   = blockIdx.x;
    const int half = lane >> 5;
    const int row  = bg * BPB + (lane & 31);

    const int2*   ch2 = (const int2*)choices;
    const float4* g4  = (const float4*)gates;
    int2     ch[R];
    uint32_t tt[R];
    #pragma unroll
    for (int r = 0; r < R; ++r) {
        ch[r] = ch2[r * G + tid];
        float4 lt = g4[r * G + tid];
        tt[r] = (lt.x != 0.0f ? 1u : 0u) | (lt.y != 0.0f ? 2u : 0u) |
                (lt.z != 0.0f ? 4u : 0u) | (lt.w != 0.0f ? 8u : 0u);
    }

    {
        const float4* xrow = (const float4*)(x + (size_t)row * W0);
        #pragma unroll
        for (int it = 0; it < 8; ++it) {
            int c = wv * 64 + it * 8 + half * 4;
            float4 v = xrow[c >> 2];
            unsigned long long m0 = __ballot(v.x != 0.0f);
            unsigned long long m1 = __ballot(v.y != 0.0f);
            unsigned long long m2 = __ballot(v.z != 0.0f);
            unsigned long long m3 = __ballot(v.w != 0.0f);
            if ((lane & 31) == 0) {
                int s = half * 32;
                cols[c + 0] = (uint32_t)(m0 >> s);
                cols[c + 1] = (uint32_t)(m1 >> s);
                cols[c + 2] = (uint32_t)(m2 >> s);
                cols[c + 3] = (uint32_t)(m3 >> s);
            }
        }
    }
    __syncthreads();

    #pragma unroll
    for (int r = 0; r < R; ++r) {
        uint32_t a = cols[ch[r].x];
        uint32_t b = cols[ch[r].y];
        uint32_t m0 = 0u - (tt[r] & 1u);
        uint32_t m1 = 0u - ((tt[r] >> 1) & 1u);
        uint32_t m2 = 0u - ((tt[r] >> 2) & 1u);
        uint32_t m3 = 0u - ((tt[r] >> 3) & 1u);
        uint32_t o = (m0 & ~a & ~b) | (m1 & ~a & b) | (m2 & a & ~b) | (m3 & a & b);
        cols[W0 + r * G + tid] = o;
        __syncthreads();
    }

    for (int w = tid * 4; w < WTOT; w += 4096) {
        uint4 c = *(const uint4*)&cols[w];
        float* orow = out + (size_t)bg * BPB * WTOT + w;
        #pragma unroll
        for (int b = 0; b < BPB; ++b) {
            vfloat4 v;
            v.x = (float)((c.x >> b) & 1u);
            v.y = (float)((c.y >> b) & 1u);
            v.z = (float)((c.z >> b) & 1u);
            v.w = (float)((c.w >> b) & 1u);
            __builtin_nontemporal_store(v, (vfloat4*)(orow + (size_t)b * WTOT));
        }
    }
}

extern "C" void kernel_launch(void* const* d_in, const int* in_sizes, int n_in,
                              void* d_out, int out_size, void* d_ws, size_t ws_size,
                              hipStream_t stream) {
    const float* x       = (const float*)d_in[0];
    const float* gates   = (const float*)d_in[1];
    const int*   choices = (const int*)d_in[2];
    float*       out     = (float*)d_out;

    const size_t packed_bytes = (size_t)NBG * WTOT * sizeof(uint32_t); // 9.44 MB
    if (d_ws != nullptr && ws_size >= packed_bytes) {
        uint32_t* packed = (uint32_t*)d_ws;
        gator_packx<<<dim3(NBG * 4), dim3(256), 0, stream>>>(x, packed);
        gator_gates<<<dim3(NBG), dim3(1024), 0, stream>>>(gates, choices, packed);
        gator_unpack<<<dim3(B), dim3(256), 0, stream>>>(packed, out);
    } else {
        gator_fused<<<dim3(B / BPB), dim3(1024), 0, stream>>>(x, gates, choices, out);
    }
}

// Round 4
// 327.799 us; speedup vs baseline: 1.0295x; 1.0295x over previous
//
#include <hip/hip_runtime.h>
#include <stdint.h>

// Gator: logic-gate network forward, bit-packed over batch. Single fused
// kernel, 256 blocks x 1024 threads, 1 block/CU (R3 structure — the measured
// winner at 328.7us).
//
// R8: revert to R3. Rounds 5-7 independently replaced the store stream
// (NT-scattered vs fill-isomorphic contiguous), the pack phase (ballot-free
// coalesced 8-blocks/CU), and the kernel structure (1 vs 2 vs 3 dispatches);
// ALL were neutral within ±9us of 330. Conclusion (Model B): the timed
// iteration is ~280us of harness re-poison (1.2GB fill @ ~190us + ~100 tiny
// memset/restore dispatches per reset), and this kernel's ~50us is already at
// its HBM floor (302MB write + 33.5MB read ~= 53us @ 6.3TB/s achievable).
// The measured structural deltas (+5.6/+2.1/+1.2us for R5/R6/R7) are exactly
// the extra-launch + workspace-round-trip costs — so fewest dispatches wins.

constexpr int B    = 8192;
constexpr int W0   = 1024;
constexpr int R    = 8;
constexpr int G    = 1024;
constexpr int WTOT = W0 + R * G;   // 9216
constexpr int BPB  = 32;           // batch bits per block

typedef float vfloat4 __attribute__((ext_vector_type(4)));

__launch_bounds__(1024, 1)
__global__ void gator_fused(const float* __restrict__ x,
                            const float* __restrict__ gates,
                            const int*   __restrict__ choices,
                            float*       __restrict__ out) {
    __shared__ uint32_t cols[WTOT];      // bit b of cols[w] = (batch b0+b, col w)

    const int tid  = threadIdx.x;
    const int lane = tid & 63;
    const int wv   = tid >> 6;           // wave id 0..15
    const int bg   = blockIdx.x;
    const int half = lane >> 5;          // 0: lanes 0-31, 1: lanes 32-63
    const int row  = bg * BPB + (lane & 31);

    // ---- Prefetch gate metadata for all 8 rows into registers ----
    // Thread tid owns gate (r, tid) for every row r. Issue these loads up
    // front so they overlap the pack phase and never sit on the barrier chain.
    const int2*   ch2 = (const int2*)choices;    // [R*G] index pairs
    const float4* g4  = (const float4*)gates;    // [R*G] truth tables
    int2     ch[R];
    uint32_t tt[R];                              // 4-bit truth table mask
    #pragma unroll
    for (int r = 0; r < R; ++r) {
        ch[r] = ch2[r * G + tid];
        float4 lt = g4[r * G + tid];
        tt[r] = (lt.x != 0.0f ? 1u : 0u) | (lt.y != 0.0f ? 2u : 0u) |
                (lt.z != 0.0f ? 4u : 0u) | (lt.w != 0.0f ? 8u : 0u);
    }

    // ---- Phase A: pack x[32 rows][1024 cols] into bit columns ----
    // Wave wv covers cols [wv*64, wv*64+64); 8 cols per iteration via ballot.
    {
        const float4* xrow = (const float4*)(x + (size_t)row * W0);
        #pragma unroll
        for (int it = 0; it < 8; ++it) {
            int c = wv * 64 + it * 8 + half * 4;
            float4 v = xrow[c >> 2];
            unsigned long long m0 = __ballot(v.x != 0.0f);
            unsigned long long m1 = __ballot(v.y != 0.0f);
            unsigned long long m2 = __ballot(v.z != 0.0f);
            unsigned long long m3 = __ballot(v.w != 0.0f);
            if ((lane & 31) == 0) {      // lane 0 -> cols c..c+3, lane 32 -> c+4..c+7
                int s = half * 32;
                cols[c + 0] = (uint32_t)(m0 >> s);
                cols[c + 1] = (uint32_t)(m1 >> s);
                cols[c + 2] = (uint32_t)(m2 >> s);
                cols[c + 3] = (uint32_t)(m3 >> s);
            }
        }
    }
    __syncthreads();

    // ---- Phase B: 8 gate rows, one gate per thread per row ----
    // All operands except the two LDS gathers are already in registers.
    #pragma unroll
    for (int r = 0; r < R; ++r) {
        uint32_t a = cols[ch[r].x];
        uint32_t b = cols[ch[r].y];
        uint32_t m0 = 0u - (tt[r] & 1u);          // broadcast each LUT bit
        uint32_t m1 = 0u - ((tt[r] >> 1) & 1u);
        uint32_t m2 = 0u - ((tt[r] >> 2) & 1u);
        uint32_t m3 = 0u - ((tt[r] >> 3) & 1u);
        uint32_t o = (m0 & ~a & ~b) | (m1 & ~a & b) | (m2 & a & ~b) | (m3 & a & b);
        cols[W0 + r * G + tid] = o;
        __syncthreads();
    }

    // ---- Phase C: unpack all 9216 columns to float32 ----
    // Thread t owns cols {4t, 4t+4096, 4t+8192}; 32 batch bits each;
    // coalesced nontemporal float4 stores (1KB/wave contiguous).
    for (int w = tid * 4; w < WTOT; w += 4096) {
        uint4 c = *(const uint4*)&cols[w];
        float* orow = out + (size_t)bg * BPB * WTOT + w;
        #pragma unroll
        for (int b = 0; b < BPB; ++b) {
            vfloat4 v;
            v.x = (float)((c.x >> b) & 1u);
            v.y = (float)((c.y >> b) & 1u);
            v.z = (float)((c.z >> b) & 1u);
            v.w = (float)((c.w >> b) & 1u);
            __builtin_nontemporal_store(v, (vfloat4*)(orow + (size_t)b * WTOT));
        }
    }
}

extern "C" void kernel_launch(void* const* d_in, const int* in_sizes, int n_in,
                              void* d_out, int out_size, void* d_ws, size_t ws_size,
                              hipStream_t stream) {
    const float* x       = (const float*)d_in[0];
    const float* gates   = (const float*)d_in[1];
    const int*   choices = (const int*)d_in[2];
    float*       out     = (float*)d_out;
    (void)d_ws; (void)ws_size;

    gator_fused<<<dim3(B / BPB), dim3(1024), 0, stream>>>(x, gates, choices, out);
}